// Round 10
// baseline (308.233 us; speedup 1.0000x reference)
//
#include <hip/hip_runtime.h>
#include <math.h>

#define EPS  1e-8f
#define C    768
#define HW   4096
#define NKB  24           // k-blocks of 32 (C/32)
#define NNB  12           // nbp2 chunks of 64 c (fast path)
#define NBN  32           // q-tiles of 128 (HW/128)
#define TAU  0.016f       // scaled-sim margin for fp32 recheck (~7 sigma of 1-pass err)
#define NCH_OLD 48        // c-chunks for fallback gather

typedef float  floatx4 __attribute__((ext_vector_type(4)));
typedef short  shortx8 __attribute__((ext_vector_type(8)));
typedef unsigned short ushort_t;
typedef unsigned int   uint_t;
typedef __attribute__((address_space(1))) uint_t as1_uint;
typedef __attribute__((address_space(3))) uint_t as3_uint;

__device__ __forceinline__ ushort_t f2bf(float v) {
    uint_t u = __float_as_uint(v);
    uint_t r = (u + 0x7FFFu + ((u >> 16) & 1u)) >> 16;   // RNE
    return (ushort_t)r;
}
__device__ __forceinline__ void async_cp16(const ushort_t* g, ushort_t* l) {
    __builtin_amdgcn_global_load_lds((const as1_uint*)g, (as3_uint*)l, 16, 0, 0);
}

// ---------------------------------------------------------------------------
// prep (z-split): per 64p x 64c tile.
//   z=0: d -> dT                    z=1: b -> bT + Bh + nbp2    z=2: a -> Ah
// Bh/Ah layout [kb][p][kk], 16B granule w at slot w ^ ((p>>1)&3).
// ---------------------------------------------------------------------------
__global__ __launch_bounds__(256) void prep_kernel(
    const float* __restrict__ a, const float* __restrict__ b,
    const float* __restrict__ d,
    ushort_t* __restrict__ Ah, ushort_t* __restrict__ Bh,
    float* __restrict__ dT, float* __restrict__ bT,
    float* __restrict__ nbp2, float* __restrict__ out)
{
    __shared__ float tile[64][65];
    const int t = threadIdx.x;
    const int p0 = blockIdx.x * 64;
    const int c0 = blockIdx.y * 64;
    const int z  = blockIdx.z;
    const int x = t & 63, y4 = t >> 6;

    if (z == 0 && blockIdx.x == 0 && blockIdx.y == 0 && t == 0) out[0] = 0.f;

    const float* src = (z == 0) ? d : (z == 1 ? b : a);
#pragma unroll
    for (int i = 0; i < 16; ++i) {
        int c = y4 * 16 + i;
        tile[c][x] = src[(size_t)(c0 + c) * HW + p0 + x];
    }
    __syncthreads();

    if (z == 0) {
#pragma unroll
        for (int i = 0; i < 16; ++i) {
            int p = y4 * 16 + i;
            dT[(size_t)(p0 + p) * C + c0 + x] = tile[x][p];
        }
        return;
    }
    if (z == 1) {
#pragma unroll
        for (int i = 0; i < 16; ++i) {
            int p = y4 * 16 + i;
            bT[(size_t)(p0 + p) * C + c0 + x] = tile[x][p];
        }
        if (t < 64) {
            float s = 0.f;
#pragma unroll
            for (int c = 0; c < 64; ++c) { float v = tile[c][t]; s += v * v; }
            nbp2[blockIdx.y * HW + p0 + t] = s;
        }
    }
    // pack tile -> (z==1 ? Bh : Ah)
    {
        const int pl = t >> 2, g = t & 3;
        const int pg = p0 + pl;
        const int sw = (pg >> 1) & 3;
        ushort_t* dst = (z == 1) ? Bh : Ah;
#pragma unroll
        for (int h = 0; h < 2; ++h) {
            const int kb = (c0 >> 5) + h;
            uint_t w[4];
#pragma unroll
            for (int u = 0; u < 4; ++u) {
                ushort_t lo = f2bf(tile[h * 32 + g * 8 + 2 * u][pl]);
                ushort_t hi = f2bf(tile[h * 32 + g * 8 + 2 * u + 1][pl]);
                w[u] = (uint_t)lo | ((uint_t)hi << 16);
            }
            uint4* oh = (uint4*)(dst + ((size_t)kb * HW + pg) * 32);
            oh[g ^ sw] = make_uint4(w[0], w[1], w[2], w[3]);
        }
    }
}

// ---------------------------------------------------------------------------
// 1-pass MFMA GEMM (Ah*Bh), BK=32 (proven R7/R9 config): per kb stage 16 KB,
// one barrier pair, 16 MFMA/wave, 8 swizzled ds_read_b128/wave. nb from nbp2
// in-block. Top-2 epilogue per 128-q tile.
// ---------------------------------------------------------------------------
__global__ __launch_bounds__(256, 4) void gemm_mfma_kernel(
    const ushort_t* __restrict__ Ah, const ushort_t* __restrict__ Bh,
    const float* __restrict__ nbp2,
    float* __restrict__ pv1, int* __restrict__ pi1,
    float* __restrict__ pv2, int* __restrict__ pi2)
{
    __shared__ __align__(16) char smem[16896];
    ushort_t* sA  = (ushort_t*)smem;             // 8 KB
    ushort_t* sB  = (ushort_t*)(smem + 8192);    // 8 KB
    float*    nb_s = (float*)(smem + 16384);     // 512 B

    const int tid  = threadIdx.x;
    const int lane = tid & 63;
    const int wave = tid >> 6;
    const int wm = wave >> 1, wn = wave & 1;
    const int bm = blockIdx.x, bn = blockIdx.y;
    const int l15 = lane & 15, l4 = lane >> 4;
    const int swz = (l15 >> 1) & 3;

    if (tid < 128) {
        float s = 0.f;
        int q = bn * 128 + tid;
#pragma unroll
        for (int ch = 0; ch < NNB; ++ch) s += nbp2[ch * HW + q];
        nb_s[tid] = 1.0f / (sqrtf(s + EPS) + EPS);
    }

    floatx4 acc[4][4];
#pragma unroll
    for (int i = 0; i < 4; ++i)
#pragma unroll
        for (int j = 0; j < 4; ++j) acc[i][j] = (floatx4){0.f, 0.f, 0.f, 0.f};

    for (int kb = 0; kb < NKB; ++kb) {
        const size_t aoff = (size_t)(kb * HW + bm * 128) * 32 + tid * 8;
        const size_t boff = (size_t)(kb * HW + bn * 128) * 32 + tid * 8;
        async_cp16(Ah + aoff,        sA + tid * 8);
        async_cp16(Ah + aoff + 2048, sA + tid * 8 + 2048);
        async_cp16(Bh + boff,        sB + tid * 8);
        async_cp16(Bh + boff + 2048, sB + tid * 8 + 2048);
        __syncthreads();

        shortx8 af[4], bf_[4];
#pragma unroll
        for (int i = 0; i < 4; ++i)
            af[i] = *(const shortx8*)&sA[((wm * 4 + i) * 16 + l15) * 32 + ((l4 ^ swz) * 8)];
#pragma unroll
        for (int j = 0; j < 4; ++j)
            bf_[j] = *(const shortx8*)&sB[((wn * 4 + j) * 16 + l15) * 32 + ((l4 ^ swz) * 8)];
#pragma unroll
        for (int i = 0; i < 4; ++i)
#pragma unroll
            for (int j = 0; j < 4; ++j)
                acc[i][j] = __builtin_amdgcn_mfma_f32_16x16x32_bf16(af[i], bf_[j], acc[i][j], 0, 0, 0);
        __syncthreads();
    }

    float rnb[4];
#pragma unroll
    for (int j = 0; j < 4; ++j)
        rnb[j] = nb_s[wn * 64 + j * 16 + l15];

    float* lv1 = (float*)smem;
    int*   li1 = (int*)(smem + 1024);
    float* lv2 = (float*)(smem + 2048);
    int*   li2 = (int*)(smem + 3072);

#pragma unroll
    for (int i = 0; i < 4; ++i) {
#pragma unroll
        for (int r = 0; r < 4; ++r) {
            float v1 = -INFINITY, v2 = -INFINITY; int i1 = 0, i2 = 0;
#pragma unroll
            for (int j = 0; j < 4; ++j) {
                float sv = acc[i][j][r] * rnb[j];
                int q = bn * 128 + wn * 64 + j * 16 + l15;
                if (sv > v1) { v2 = v1; i2 = i1; v1 = sv; i1 = q; }
                else if (sv > v2) { v2 = sv; i2 = q; }
            }
#pragma unroll
            for (int m = 1; m < 16; m <<= 1) {
                float ov1 = __shfl_xor(v1, m, 64);
                int   oi1 = __shfl_xor(i1, m, 64);
                float ov2 = __shfl_xor(v2, m, 64);
                int   oi2 = __shfl_xor(i2, m, 64);
                if (ov1 > v1 || (ov1 == v1 && oi1 < i1)) {
                    if (v1 > ov2 || (v1 == ov2 && i1 < oi2)) { v2 = v1; i2 = i1; }
                    else { v2 = ov2; i2 = oi2; }
                    v1 = ov1; i1 = oi1;
                } else if (ov1 > v2 || (ov1 == v2 && oi1 < i2)) {
                    v2 = ov1; i2 = oi1;
                }
            }
            if (l15 == 0) {
                int pl = wm * 64 + i * 16 + l4 * 4 + r;
                lv1[pl * 2 + wn] = v1; li1[pl * 2 + wn] = i1;
                lv2[pl * 2 + wn] = v2; li2[pl * 2 + wn] = i2;
            }
        }
    }
    __syncthreads();
    if (tid < 128) {
        float v1 = lv1[tid * 2],     v2 = lv2[tid * 2];
        int   i1 = li1[tid * 2],     i2 = li2[tid * 2];
        float w1 = lv1[tid * 2 + 1], w2 = lv2[tid * 2 + 1];
        int   j1 = li1[tid * 2 + 1], j2 = li2[tid * 2 + 1];
        if (w1 > v1 || (w1 == v1 && j1 < i1)) {
            if (v1 > w2 || (v1 == w2 && i1 < j2)) { v2 = v1; i2 = i1; }
            else { v2 = w2; i2 = j2; }
            v1 = w1; i1 = j1;
        } else if (w1 > v2 || (w1 == v2 && j1 < i2)) {
            v2 = w1; i2 = j1;
        }
        int p = bm * 128 + tid;
        pv1[p * NBN + bn] = v1; pi1[p * NBN + bn] = i1;
        pv2[p * NBN + bn] = v2; pi2[p * NBN + bn] = i2;
    }
}

// ---------------------------------------------------------------------------
// gather_finish: block = 64p x 64c. Phase A: each wave merges top-2 for 16
// rows (redundant across the 12 c-chunks — no sync needed) + fp32 recheck of
// flagged rows via bT; qs stays in LDS; c-chunk 0 writes out_zbest.
// Phase B: gather z_new from dT, write coalesced, loss partials.
// ---------------------------------------------------------------------------
__global__ __launch_bounds__(256) void gather_finish_kernel(
    const float* __restrict__ a, const float* __restrict__ bT,
    const float* __restrict__ dT,
    const float* __restrict__ pv1, const int* __restrict__ pi1,
    const float* __restrict__ pv2, const int* __restrict__ pi2,
    float* __restrict__ out,
    float* __restrict__ pdot, float* __restrict__ pa2, float* __restrict__ pt2)
{
    __shared__ float tile[64][65];
    __shared__ int qs[64];
    const int t = threadIdx.x;
    const int wv = t >> 6, lane = t & 63;
    const int p0 = blockIdx.x * 64;
    const int c0 = blockIdx.y * 64;
    float* out_zbest = out + 1 + (size_t)C * HW;

    // ---- phase A: zb for 16 rows per wave
    for (int r = 0; r < 16; ++r) {
        const int pl = wv * 16 + r;
        const int p = p0 + pl;
        const int tq = lane & 31;
        float v1, v2; int i1, cand;
        if (lane < 32) {
            v1 = pv1[p * NBN + tq]; i1 = pi1[p * NBN + tq]; v2 = pv2[p * NBN + tq];
            cand = i1;
        } else {
            v1 = -INFINITY; v2 = -INFINITY; i1 = 0x7fffffff;
            cand = pi2[p * NBN + tq];
        }
#pragma unroll
        for (int m = 1; m < 32; m <<= 1) {
            float ov1 = __shfl_xor(v1, m, 64);
            int   oi1 = __shfl_xor(i1, m, 64);
            float ov2 = __shfl_xor(v2, m, 64);
            if (ov1 > v1 || (ov1 == v1 && oi1 < i1)) {
                v2 = fmaxf(v1, ov2); v1 = ov1; i1 = oi1;
            } else {
                v2 = fmaxf(v2, ov1);
            }
        }
        v1 = __shfl(v1, 0, 64); v2 = __shfl(v2, 0, 64); i1 = __shfl(i1, 0, 64);

        int zq = i1;
        if (v1 - v2 < TAU) {
            int q = cand;
            float dot = 0.f, b2 = 0.f;
            const float* br = bT + (size_t)q * C;
            const float* ap = a + p;
#pragma unroll 4
            for (int c = 0; c < C; c += 4) {
                float4 bv = *(const float4*)(br + c);
                dot += ap[(size_t)c * HW] * bv.x + ap[(size_t)(c + 1) * HW] * bv.y
                     + ap[(size_t)(c + 2) * HW] * bv.z + ap[(size_t)(c + 3) * HW] * bv.w;
                b2  += bv.x * bv.x + bv.y * bv.y + bv.z * bv.z + bv.w * bv.w;
            }
            float s = dot / (sqrtf(b2 + EPS) + EPS);
#pragma unroll
            for (int m = 1; m < 64; m <<= 1) {
                float os = __shfl_xor(s, m, 64);
                int   oq = __shfl_xor(q, m, 64);
                if (os > s || (os == s && oq < q)) { s = os; q = oq; }
            }
            zq = q;
        }
        if (lane == 0) {
            qs[pl] = zq;
            if (blockIdx.y == 0) out_zbest[p] = (float)zq;
        }
    }
    __syncthreads();

    // ---- phase B: gather + z_new write + loss partials
    {
        const int pl = t >> 2, sub = t & 3;
        const float* src = dT + (size_t)qs[pl] * C + c0 + sub * 16;
        float4 v0 = *(const float4*)(src);
        float4 v1 = *(const float4*)(src + 4);
        float4 v2 = *(const float4*)(src + 8);
        float4 v3 = *(const float4*)(src + 12);
        float* dst = &tile[pl][sub * 16];
        dst[0] = v0.x; dst[1] = v0.y; dst[2]  = v0.z; dst[3]  = v0.w;
        dst[4] = v1.x; dst[5] = v1.y; dst[6]  = v1.z; dst[7]  = v1.w;
        dst[8] = v2.x; dst[9] = v2.y; dst[10] = v2.z; dst[11] = v2.w;
        dst[12] = v3.x; dst[13] = v3.y; dst[14] = v3.z; dst[15] = v3.w;
    }
    __syncthreads();

    const int p = t & 63, cg = t >> 6;
    float dot = 0.f, a2 = 0.f, t2 = 0.f;
#pragma unroll
    for (int i = 0; i < 16; ++i) {
        int cc = cg * 16 + i;
        float tv = tile[p][cc];
        float av = a[(size_t)(c0 + cc) * HW + p0 + p];
        out[1 + (size_t)(c0 + cc) * HW + p0 + p] = tv;
        dot += av * tv; a2 += av * av; t2 += tv * tv;
    }
    __shared__ float r1[256], r2[256], r3[256];
    r1[t] = dot; r2[t] = a2; r3[t] = t2;
    __syncthreads();
    if (t < 64) {
        dot = r1[t] + r1[t + 64] + r1[t + 128] + r1[t + 192];
        a2  = r2[t] + r2[t + 64] + r2[t + 128] + r2[t + 192];
        t2  = r3[t] + r3[t + 64] + r3[t + 128] + r3[t + 192];
        pdot[blockIdx.y * HW + p0 + t] = dot;
        pa2[blockIdx.y * HW + p0 + t]  = a2;
        pt2[blockIdx.y * HW + p0 + t]  = t2;
    }
}

__global__ __launch_bounds__(256) void loss_finalize_kernel(
    const float* __restrict__ pdot, const float* __restrict__ pa2,
    const float* __restrict__ pt2, float* __restrict__ out, int nch)
{
    int p = blockIdx.x * 256 + threadIdx.x;
    float dot = 0.f, a2 = 0.f, t2 = 0.f;
#pragma unroll 12
    for (int ch = 0; ch < nch; ++ch) {
        dot += pdot[ch * HW + p];
        a2  += pa2[ch * HW + p];
        t2  += pt2[ch * HW + p];
    }
    float cs = dot / ((sqrtf(a2) + EPS) * (sqrtf(t2) + EPS));
    float contrib = 1.f - cs;
    __shared__ float red[256];
    red[threadIdx.x] = contrib;
    __syncthreads();
    for (int s = 128; s > 0; s >>= 1) {
        if (threadIdx.x < s) red[threadIdx.x] += red[threadIdx.x + s];
        __syncthreads();
    }
    if (threadIdx.x == 0) atomicAdd(out, red[0] * (1.0f / HW));
}

// ---------------------------------------------------------------------------
// fp32 fallback path (only if workspace is unexpectedly small)
// ---------------------------------------------------------------------------
__global__ __launch_bounds__(256) void bnorm_partial_fb_kernel(
    const float* __restrict__ b, float* __restrict__ nbp)
{
    int q = blockIdx.x * 256 + threadIdx.x;
    int c0 = blockIdx.y * 32;
    float s = 0.f;
#pragma unroll 8
    for (int c = c0; c < c0 + 32; ++c) { float v = b[c * HW + q]; s += v * v; }
    nbp[blockIdx.y * HW + q] = s;
}

__global__ __launch_bounds__(256) void bnorm_finalize_fb_kernel(
    const float* __restrict__ nbp, float* __restrict__ nb)
{
    int q = blockIdx.x * 256 + threadIdx.x;
    float s = 0.f;
#pragma unroll
    for (int ch = 0; ch < NKB; ++ch) s += nbp[ch * HW + q];
    nb[q] = sqrtf(s + EPS) + EPS;
}

__global__ __launch_bounds__(256) void gemm_argmax_fb_kernel(
    const float* __restrict__ A, const float* __restrict__ B,
    const float* __restrict__ nb,
    float* __restrict__ pval, int* __restrict__ pidx)
{
    __shared__ __align__(16) char smem[16384];
    float (*As)[128] = (float (*)[128])smem;
    float (*Bs)[128] = (float (*)[128])(smem + 4096);
    const int m0 = blockIdx.x * 128, q0 = blockIdx.y * 128;
    const int tid = threadIdx.x;
    const int tx = tid & 15, ty = tid >> 4;
    const int lr = tid >> 5, lc = (tid & 31) * 4;
    float acc[8][8] = {};
    for (int k0 = 0; k0 < C; k0 += 8) {
        *(float4*)&As[lr][lc] = *(const float4*)&A[(k0 + lr) * HW + m0 + lc];
        *(float4*)&Bs[lr][lc] = *(const float4*)&B[(k0 + lr) * HW + q0 + lc];
        __syncthreads();
#pragma unroll
        for (int kk = 0; kk < 8; ++kk) {
            float a8[8], b8[8];
            *(float4*)&a8[0] = *(float4*)&As[kk][ty * 8];
            *(float4*)&a8[4] = *(float4*)&As[kk][ty * 8 + 4];
            *(float4*)&b8[0] = *(float4*)&Bs[kk][tx * 8];
            *(float4*)&b8[4] = *(float4*)&Bs[kk][tx * 8 + 4];
#pragma unroll
            for (int i = 0; i < 8; ++i)
#pragma unroll
                for (int j = 0; j < 8; ++j) acc[i][j] += a8[i] * b8[j];
        }
        __syncthreads();
    }
    float nbv[8];
#pragma unroll
    for (int j = 0; j < 8; ++j) nbv[j] = nb[q0 + tx * 8 + j];
    float (*rv)[16] = (float (*)[16])smem;
    int   (*ri)[16] = (int   (*)[16])(smem + 8192);
#pragma unroll
    for (int i = 0; i < 8; ++i) {
        float bv = -INFINITY; int bi = 0;
#pragma unroll
        for (int j = 0; j < 8; ++j) {
            float s = acc[i][j] / nbv[j];
            int q = q0 + tx * 8 + j;
            if (s > bv) { bv = s; bi = q; }
        }
        rv[ty * 8 + i][tx] = bv;
        ri[ty * 8 + i][tx] = bi;
    }
    __syncthreads();
    if (tid < 128) {
        float bv = rv[tid][0]; int bi = ri[tid][0];
#pragma unroll
        for (int t = 1; t < 16; ++t) {
            float v = rv[tid][t]; int ii = ri[tid][t];
            if (v > bv || (v == bv && ii < bi)) { bv = v; bi = ii; }
        }
        pval[(m0 + tid) * NBN + blockIdx.y] = bv;
        pidx[(m0 + tid) * NBN + blockIdx.y] = bi;
    }
}

__global__ __launch_bounds__(256) void reduce_fb_kernel(
    const float* __restrict__ pval, const int* __restrict__ pidx,
    int* __restrict__ zb, float* __restrict__ out_zbest)
{
    int p = blockIdx.x * 256 + threadIdx.x;
    float bv = pval[p * NBN]; int bi = pidx[p * NBN];
#pragma unroll 8
    for (int t = 1; t < NBN; ++t) {
        float v = pval[p * NBN + t]; int ii = pidx[p * NBN + t];
        if (v > bv || (v == bv && ii < bi)) { bv = v; bi = ii; }
    }
    zb[p] = bi;
    out_zbest[p] = (float)bi;
}

__global__ __launch_bounds__(256) void gather_partial_kernel(
    const float* __restrict__ a, const float* __restrict__ d,
    const int* __restrict__ zb, float* __restrict__ out,
    float* __restrict__ pdot, float* __restrict__ pa2, float* __restrict__ pt2)
{
    int p = blockIdx.x * 256 + threadIdx.x;
    int ch = blockIdx.y;
    int c0 = ch * (C / NCH_OLD);
    int q = zb[p];
    float dot = 0.f, a2 = 0.f, t2 = 0.f;
#pragma unroll
    for (int c = c0; c < c0 + C / NCH_OLD; ++c) {
        float av = a[c * HW + p];
        float tv = d[c * HW + q];
        dot += av * tv; a2 += av * av; t2 += tv * tv;
        out[1 + c * HW + p] = tv;
    }
    pdot[ch * HW + p] = dot;
    pa2[ch * HW + p] = a2;
    pt2[ch * HW + p] = t2;
}

extern "C" void kernel_launch(void* const* d_in, const int* in_sizes, int n_in,
                              void* d_out, int out_size, void* d_ws, size_t ws_size,
                              hipStream_t stream) {
    const float* a = (const float*)d_in[0];
    const float* b = (const float*)d_in[1];
    const float* d = (const float*)d_in[2];
    float* out = (float*)d_out;
    float* out_zbest = out + 1 + (size_t)C * HW;

    char* ws = (char*)d_ws;
    size_t off = 0;
    auto alloc = [&](size_t bytes) { void* p = ws + off; off = (off + bytes + 255) & ~(size_t)255; return p; };

    const size_t PACK = (size_t)C * HW * 2;  // 6.29 MB
    ushort_t* Ah = (ushort_t*)alloc(PACK);
    ushort_t* Bh = (ushort_t*)alloc(PACK);
    float* nbp = (float*)alloc((size_t)NKB * HW * 4);
    float* pv1 = (float*)alloc((size_t)HW * NBN * 4);
    int*   pi1 = (int*)alloc((size_t)HW * NBN * 4);
    float* pv2 = (float*)alloc((size_t)HW * NBN * 4);
    int*   pi2 = (int*)alloc((size_t)HW * NBN * 4);
    float* pdot = (float*)alloc((size_t)NNB * HW * 4);
    float* pa2  = (float*)alloc((size_t)NNB * HW * 4);
    float* pt2  = (float*)alloc((size_t)NNB * HW * 4);
    float* dT  = (float*)alloc((size_t)C * HW * 4);   // 12.6 MB
    float* bT  = (float*)alloc((size_t)C * HW * 4);   // 12.6 MB
    bool fast = off <= ws_size;                       // ~41 MB

    if (fast) {
        prep_kernel<<<dim3(HW / 64, C / 64, 3), 256, 0, stream>>>(
            a, b, d, Ah, Bh, dT, bT, nbp, out);
        gemm_mfma_kernel<<<dim3(HW / 128, HW / 128), 256, 0, stream>>>(
            Ah, Bh, nbp, pv1, pi1, pv2, pi2);
        gather_finish_kernel<<<dim3(HW / 64, NNB), 256, 0, stream>>>(
            a, bT, dT, pv1, pi1, pv2, pi2, out, pdot, pa2, pt2);
        loss_finalize_kernel<<<HW / 256, 256, 0, stream>>>(pdot, pa2, pt2, out, NNB);
    } else {
        // compact fp32 fallback
        off = 0;
        float* nb = (float*)alloc(HW * 4);
        nbp = (float*)alloc((size_t)NKB * HW * 4);
        pv1 = (float*)alloc((size_t)HW * NBN * 4);
        pi1 = (int*)alloc((size_t)HW * NBN * 4);
        int* zb = (int*)alloc(HW * 4);
        float* pdot2 = (float*)alloc((size_t)NCH_OLD * HW * 4);
        float* pa22  = (float*)alloc((size_t)NCH_OLD * HW * 4);
        float* pt22  = (float*)alloc((size_t)NCH_OLD * HW * 4);
        hipMemsetAsync(d_out, 0, sizeof(float), stream);
        bnorm_partial_fb_kernel<<<dim3(HW / 256, NKB), 256, 0, stream>>>(b, nbp);
        bnorm_finalize_fb_kernel<<<HW / 256, 256, 0, stream>>>(nbp, nb);
        gemm_argmax_fb_kernel<<<dim3(HW / 128, HW / 128), 256, 0, stream>>>(a, b, nb, pv1, pi1);
        reduce_fb_kernel<<<HW / 256, 256, 0, stream>>>(pv1, pi1, zb, out_zbest);
        gather_partial_kernel<<<dim3(HW / 256, NCH_OLD), 256, 0, stream>>>(
            a, d, zb, out, pdot2, pa22, pt22);
        loss_finalize_kernel<<<HW / 256, 256, 0, stream>>>(pdot2, pa22, pt22, out, NCH_OLD);
    }
}